// Round 1
// baseline (503.571 us; speedup 1.0000x reference)
//
#include <hip/hip_runtime.h>

// GAT layer: N=8192, IN_DIM=128, OUT_DIM=64, alpha=0.2
// inputs: x[8192,128] f32, adj[8192,8192] i32, W[128,64] f32, a[128,1] f32
// out: elu( softmax_row( mask(lrelu(s1_i + s2_j), adj) ) @ Wh )  [8192,64] f32

#define N 8192
#define IN_DIM 128
#define OUT_DIM 64
#define ALPHA 0.2f

typedef _Float16 half8 __attribute__((ext_vector_type(8)));
typedef float f32x4 __attribute__((ext_vector_type(4)));

// ---------------------------------------------------------------------------
// Kernel 1: Wh[i,:] = x[i,:] @ W ; s1[i] = Wh[i,:]·a1 ; s2[i] = Wh[i,:]·a2
// Writes Wh transposed as fp16: Wh_t[f*8192 + i], so the attention kernel can
// load MFMA B-fragments (8 consecutive k for fixed f) as contiguous b128.
// ---------------------------------------------------------------------------
__global__ __launch_bounds__(64) void wh_kernel(
    const float* __restrict__ x, const float* __restrict__ W,
    const float* __restrict__ a, _Float16* __restrict__ Wh_t,
    float* __restrict__ s1, float* __restrict__ s2) {
  __shared__ float xs[IN_DIM];
  const int i = blockIdx.x;
  const int t = threadIdx.x;  // 0..63, = output feature f

  xs[t]      = x[(size_t)i * IN_DIM + t];
  xs[t + 64] = x[(size_t)i * IN_DIM + 64 + t];
  __syncthreads();

  float wh = 0.f;
#pragma unroll
  for (int d = 0; d < IN_DIM; ++d) wh = fmaf(xs[d], W[d * OUT_DIM + t], wh);

  Wh_t[(size_t)t * N + i] = (_Float16)wh;

  float p1 = wh * a[t];
  float p2 = wh * a[64 + t];
#pragma unroll
  for (int off = 32; off; off >>= 1) {
    p1 += __shfl_down(p1, off);
    p2 += __shfl_down(p2, off);
  }
  if (t == 0) {
    s1[i] = p1;
    s2[i] = p2;
  }
}

// ---------------------------------------------------------------------------
// Kernel 2: M = lrelu(max(s1) + max(s2))  — global upper bound on all scores.
// exp(score - M) <= 1 for every (i,j), so fp16 P never overflows, and the
// softmax ratios are mathematically identical to the reference's per-row max.
// ---------------------------------------------------------------------------
__global__ __launch_bounds__(256) void max_kernel(
    const float* __restrict__ s1, const float* __restrict__ s2,
    float* __restrict__ Mout) {
  __shared__ float red[8];
  const int t = threadIdx.x;
  float m1 = -1e30f, m2 = -1e30f;
  for (int idx = t; idx < N; idx += 256) {
    m1 = fmaxf(m1, s1[idx]);
    m2 = fmaxf(m2, s2[idx]);
  }
#pragma unroll
  for (int off = 32; off; off >>= 1) {
    m1 = fmaxf(m1, __shfl_down(m1, off));
    m2 = fmaxf(m2, __shfl_down(m2, off));
  }
  if ((t & 63) == 0) {
    red[t >> 6] = m1;
    red[4 + (t >> 6)] = m2;
  }
  __syncthreads();
  if (t == 0) {
    m1 = fmaxf(fmaxf(red[0], red[1]), fmaxf(red[2], red[3]));
    m2 = fmaxf(fmaxf(red[4], red[5]), fmaxf(red[6], red[7]));
    float e = m1 + m2;
    Mout[0] = e > 0.f ? e : ALPHA * e;
  }
}

// ---------------------------------------------------------------------------
// Kernel 3: the adj streamer. 256 blocks x 32 rows. Per 64-col tile:
//   phase A: stage Wh tile (fp16, [f][j] layout), load adj int4s, build fp16
//            P tile in LDS, accumulate row sums l (f32, from fp16-rounded p).
//   phase B: 2 K-steps x 2 row-halves of mfma_f32_16x16x32_f16 per wave.
// Epilogue: out = elu(acc / l).
// LDS row stride 72 halfs = 144 B (16B-aligned, breaks pow2 bank patterns).
// ---------------------------------------------------------------------------
#define BI 32      // rows per block
#define BJ 64      // j-tile
#define LDP 72     // padded LDS row stride (halfs)

__global__ __launch_bounds__(256) void attn_kernel(
    const int* __restrict__ adj, const _Float16* __restrict__ Wh_t,
    const float* __restrict__ s1, const float* __restrict__ s2,
    const float* __restrict__ Mptr, float* __restrict__ out) {
  __shared__ __align__(16) _Float16 Ps[BI * LDP];
  __shared__ __align__(16) _Float16 Whs[BJ * LDP];
  __shared__ float lsum[BI];
  __shared__ float s1s[BI];

  const int t = threadIdx.x;
  const int i0 = blockIdx.x * BI;
  const float M = Mptr[0];

  if (t < BI) {
    lsum[t] = 0.f;
    s1s[t] = s1[i0 + t];
  }
  __syncthreads();

  // phase-A indexing: thread covers row ii, cols c8*8 .. c8*8+7
  const int ii = t >> 3;
  const int c8 = t & 7;
  // MFMA indexing
  const int w = t >> 6;        // wave 0..3 -> output cols w*16..
  const int lane = t & 63;
  const int q = lane >> 4;     // quad
  const int r16 = lane & 15;

  f32x4 acc0 = {0.f, 0.f, 0.f, 0.f};  // rows 0..15 of block tile
  f32x4 acc1 = {0.f, 0.f, 0.f, 0.f};  // rows 16..31

  for (int jt = 0; jt < N / BJ; ++jt) {
    const int j0 = jt * BJ;

    // ---- stage Wh tile: Whs[f][jj], f = t>>2 (0..63), 16 halfs per thread
    {
      const int f = t >> 2, part = t & 3;
      const uint4* src = (const uint4*)(Wh_t + (size_t)f * N + j0 + part * 16);
      uint4 v0 = src[0];
      uint4 v1 = src[1];
      *(uint4*)(&Whs[f * LDP + part * 16]) = v0;
      *(uint4*)(&Whs[f * LDP + part * 16 + 8]) = v1;
    }

    // ---- P tile: p = adj ? exp(lrelu(s1+s2) - M) : 0, as fp16
    {
      const size_t base = (size_t)(i0 + ii) * N + j0 + c8 * 8;
      const int4 a0 = *(const int4*)(adj + base);
      const int4 a1 = *(const int4*)(adj + base + 4);
      const float4 sa = *(const float4*)(s2 + j0 + c8 * 8);
      const float4 sb = *(const float4*)(s2 + j0 + c8 * 8 + 4);
      const float s1v = s1s[ii];
      const float se[8] = {sa.x, sa.y, sa.z, sa.w, sb.x, sb.y, sb.z, sb.w};
      const int av[8] = {a0.x, a0.y, a0.z, a0.w, a1.x, a1.y, a1.z, a1.w};
      half8 hp;
      float psum = 0.f;
#pragma unroll
      for (int c = 0; c < 8; ++c) {
        float e = s1v + se[c];
        e = e > 0.f ? e : ALPHA * e;
        float pv = __expf(e - M);
        pv = av[c] > 0 ? pv : 0.f;
        _Float16 h = (_Float16)pv;
        hp[c] = h;
        psum += (float)h;  // sum the fp16-rounded value: consistent normalizer
      }
      *(half8*)(&Ps[ii * LDP + c8 * 8]) = hp;
      psum += __shfl_xor(psum, 1);
      psum += __shfl_xor(psum, 2);
      psum += __shfl_xor(psum, 4);
      if (c8 == 0) lsum[ii] += psum;
    }
    __syncthreads();

    // ---- MFMA: C[32x64] += P[32x64] @ Wh[64x64]
    // A-frag: A[m=lane&15][k=q*8+j]  (verified layout, m120)
    // B-frag: B[k=q*8+j][n=lane&15]  -> contiguous in Whs[n][k]
#pragma unroll
    for (int ks = 0; ks < 2; ++ks) {
      const int kb = ks * 32 + q * 8;
      half8 bf = *(const half8*)(&Whs[(w * 16 + r16) * LDP + kb]);
      half8 aA = *(const half8*)(&Ps[r16 * LDP + kb]);
      half8 aB = *(const half8*)(&Ps[(16 + r16) * LDP + kb]);
      acc0 = __builtin_amdgcn_mfma_f32_16x16x32_f16(aA, bf, acc0, 0, 0, 0);
      acc1 = __builtin_amdgcn_mfma_f32_16x16x32_f16(aB, bf, acc1, 0, 0, 0);
    }
    __syncthreads();  // protect Ps/Whs before next tile's stores
  }

  // ---- epilogue: out = elu(acc / l). C/D: row = q*4+reg, col = lane&15.
#pragma unroll
  for (int h = 0; h < 2; ++h) {
    const f32x4 acc = h ? acc1 : acc0;
#pragma unroll
    for (int r = 0; r < 4; ++r) {
      const int m = q * 4 + r;
      const float l = lsum[h * 16 + m];
      float v = acc[r] / l;
      v = v > 0.f ? v : expm1f(v);
      out[(size_t)(i0 + h * 16 + m) * OUT_DIM + w * 16 + r16] = v;
    }
  }
}

// ---------------------------------------------------------------------------
extern "C" void kernel_launch(void* const* d_in, const int* in_sizes, int n_in,
                              void* d_out, int out_size, void* d_ws,
                              size_t ws_size, hipStream_t stream) {
  const float* x = (const float*)d_in[0];
  const int* adj = (const int*)d_in[1];
  const float* W = (const float*)d_in[2];
  const float* a = (const float*)d_in[3];
  float* out = (float*)d_out;

  char* ws = (char*)d_ws;
  _Float16* Wh_t = (_Float16*)ws;                       // 8192*64*2 = 1 MiB
  float* s1 = (float*)(ws + (size_t)N * OUT_DIM * 2);   // 32 KiB
  float* s2 = s1 + N;                                   // 32 KiB
  float* M = s2 + N;                                    // 4 B

  wh_kernel<<<N, 64, 0, stream>>>(x, W, a, Wh_t, s1, s2);
  max_kernel<<<1, 256, 0, stream>>>(s1, s2, M);
  attn_kernel<<<N / BI, 256, 0, stream>>>(adj, Wh_t, s1, s2, M, out);
}

// Round 2
// 442.715 us; speedup vs baseline: 1.1375x; 1.1375x over previous
//
#include <hip/hip_runtime.h>

// GAT layer: N=8192, IN_DIM=128, OUT_DIM=64, alpha=0.2
// out = elu( softmax_row( mask(lrelu(s1_i + s2_j), adj) ) @ Wh )
//
// R2: latency-bound fix. attn kernel restructured: no LDS, no barriers,
// j-split into JC=8 chunks (grid 1024 = 4 blocks/CU = 16 waves/CU vs R1's
// 1 block/CU). Each wave owns 16 rows x 64 features; P is built directly in
// MFMA A-fragment layout in registers; B-frags load straight from
// L2-resident Wh_t. Partial (acc,l) per chunk -> reduce kernel.

#define N 8192
#define IN_DIM 128
#define OUT_DIM 64
#define ALPHA 0.2f
#define JC 8                  // j-chunks (parallelism multiplier)
#define JTILES (N / JC / 64)  // 16 tiles of 64 cols per chunk

typedef _Float16 half8 __attribute__((ext_vector_type(8)));
typedef float f32x4 __attribute__((ext_vector_type(4)));

// ---------------------------------------------------------------------------
// Kernel 1: Wh = x@W (fp16, transposed [f][i]) ; s1 = Wh·a1 ; s2 = Wh·a2
// ---------------------------------------------------------------------------
__global__ __launch_bounds__(64) void wh_kernel(
    const float* __restrict__ x, const float* __restrict__ W,
    const float* __restrict__ a, _Float16* __restrict__ Wh_t,
    float* __restrict__ s1, float* __restrict__ s2) {
  __shared__ float xs[IN_DIM];
  const int i = blockIdx.x;
  const int t = threadIdx.x;  // 0..63 = output feature f

  xs[t]      = x[(size_t)i * IN_DIM + t];
  xs[t + 64] = x[(size_t)i * IN_DIM + 64 + t];
  __syncthreads();

  float wh = 0.f;
#pragma unroll
  for (int d = 0; d < IN_DIM; ++d) wh = fmaf(xs[d], W[d * OUT_DIM + t], wh);

  Wh_t[(size_t)t * N + i] = (_Float16)wh;

  float p1 = wh * a[t];
  float p2 = wh * a[64 + t];
#pragma unroll
  for (int off = 32; off; off >>= 1) {
    p1 += __shfl_down(p1, off);
    p2 += __shfl_down(p2, off);
  }
  if (t == 0) {
    s1[i] = p1;
    s2[i] = p2;
  }
}

// ---------------------------------------------------------------------------
// Kernel 2: M = lrelu(max(s1)+max(s2)) — global score upper bound.
// exp(score-M) <= 1 always -> fp16-safe, softmax ratios unchanged, and the
// normalizer/accumulator become fully associative over j (enables j-split).
// ---------------------------------------------------------------------------
__global__ __launch_bounds__(256) void max_kernel(
    const float* __restrict__ s1, const float* __restrict__ s2,
    float* __restrict__ Mout) {
  __shared__ float red[8];
  const int t = threadIdx.x;
  float m1 = -1e30f, m2 = -1e30f;
  for (int idx = t; idx < N; idx += 256) {
    m1 = fmaxf(m1, s1[idx]);
    m2 = fmaxf(m2, s2[idx]);
  }
#pragma unroll
  for (int off = 32; off; off >>= 1) {
    m1 = fmaxf(m1, __shfl_down(m1, off));
    m2 = fmaxf(m2, __shfl_down(m2, off));
  }
  if ((t & 63) == 0) {
    red[t >> 6] = m1;
    red[4 + (t >> 6)] = m2;
  }
  __syncthreads();
  if (t == 0) {
    m1 = fmaxf(fmaxf(red[0], red[1]), fmaxf(red[2], red[3]));
    m2 = fmaxf(fmaxf(red[4], red[5]), fmaxf(red[6], red[7]));
    float e = m1 + m2;
    Mout[0] = e > 0.f ? e : ALPHA * e;
  }
}

// ---------------------------------------------------------------------------
// Kernel 3: adj streamer. grid (N/64, JC); wave w owns rows
// blockIdx.x*64 + w*16 .. +15, j in [c*1024, (c+1)*1024).
// No LDS, no barriers. Lane (q=lane>>4, r16=lane&15):
//   A-frag (mfma_f32_16x16x32_f16): A[m=r16][k=q*8+j]  -> lane loads adj row
//   (i0+r16), cols j0+ks*32+q*8..+7, computes p in-register.
//   B-frag: B[k=q*8+j][n=r16] -> contiguous half8 from Wh_t[n*N + j0+k].
//   C/D: row=q*4+reg, col=r16  (layouts verified by R1 pass).
// ---------------------------------------------------------------------------
__global__ __launch_bounds__(256, 4) void attn_kernel(
    const int* __restrict__ adj, const _Float16* __restrict__ Wh_t,
    const float* __restrict__ s1, const float* __restrict__ s2,
    const float* __restrict__ Mptr, float* __restrict__ accp,
    float* __restrict__ lp) {
  const int t = threadIdx.x;
  const int w = t >> 6;
  const int lane = t & 63;
  const int q = lane >> 4;
  const int r16 = lane & 15;
  const int i0 = blockIdx.x * 64 + w * 16;  // wave's 16-row group
  const int c = blockIdx.y;                 // j-chunk
  const int jbase = c * (N / JC);

  const float M = Mptr[0];
  const float s1v = s1[i0 + r16];
  const size_t arow = (size_t)(i0 + r16) * N;

  f32x4 acc[4] = {{0.f, 0.f, 0.f, 0.f},
                  {0.f, 0.f, 0.f, 0.f},
                  {0.f, 0.f, 0.f, 0.f},
                  {0.f, 0.f, 0.f, 0.f}};
  float lacc = 0.f;

  for (int jt = 0; jt < JTILES; ++jt) {
    const int j0 = jbase + jt * 64;

    // ---- build A-frags (P tile) in registers
    half8 aF[2];
#pragma unroll
    for (int ks = 0; ks < 2; ++ks) {
      const int kb = ks * 32 + q * 8;
      const int4 a0 = *(const int4*)(adj + arow + j0 + kb);
      const int4 a1 = *(const int4*)(adj + arow + j0 + kb + 4);
      const float4 sa = *(const float4*)(s2 + j0 + kb);
      const float4 sb = *(const float4*)(s2 + j0 + kb + 4);
      const int av[8] = {a0.x, a0.y, a0.z, a0.w, a1.x, a1.y, a1.z, a1.w};
      const float sv[8] = {sa.x, sa.y, sa.z, sa.w, sb.x, sb.y, sb.z, sb.w};
#pragma unroll
      for (int cc = 0; cc < 8; ++cc) {
        float e = s1v + sv[cc];
        e = e > 0.f ? e : ALPHA * e;
        float pv = __expf(e - M);
        pv = av[cc] > 0 ? pv : 0.f;
        _Float16 h = (_Float16)pv;
        aF[ks][cc] = h;
        lacc += (float)h;  // fp16-rounded sum == MFMA numerator terms
      }
    }

    // ---- B-frags from L2-resident Wh_t + MFMA
#pragma unroll
    for (int ks = 0; ks < 2; ++ks) {
      const int kb = ks * 32 + q * 8;
#pragma unroll
      for (int fg = 0; fg < 4; ++fg) {
        const half8 bf =
            *(const half8*)(Wh_t + (size_t)(fg * 16 + r16) * N + j0 + kb);
        acc[fg] = __builtin_amdgcn_mfma_f32_16x16x32_f16(aF[ks], bf, acc[fg],
                                                         0, 0, 0);
      }
    }
  }

  // row sum: lanes sharing r16 (4 q-values) hold disjoint col partials
  lacc += __shfl_xor(lacc, 16);
  lacc += __shfl_xor(lacc, 32);
  if (q == 0) lp[(size_t)c * N + i0 + r16] = lacc;

  // store acc partials; C/D row = q*4+reg, col = fg*16+r16
#pragma unroll
  for (int fg = 0; fg < 4; ++fg) {
#pragma unroll
    for (int r = 0; r < 4; ++r) {
      const int row = i0 + q * 4 + r;
      accp[((size_t)c * N + row) * OUT_DIM + fg * 16 + r16] = acc[fg][r];
    }
  }
}

// ---------------------------------------------------------------------------
// Kernel 4: combine JC partials, normalize, ELU.
// ---------------------------------------------------------------------------
__global__ __launch_bounds__(256) void reduce_kernel(
    const float* __restrict__ accp, const float* __restrict__ lp,
    float* __restrict__ out) {
  const int tid = blockIdx.x * 256 + threadIdx.x;  // over N*OUT_DIM
  const int i = tid >> 6;                          // row
  float s = 0.f, l = 0.f;
#pragma unroll
  for (int c = 0; c < JC; ++c) s += accp[(size_t)c * N * OUT_DIM + tid];
#pragma unroll
  for (int c = 0; c < JC; ++c) l += lp[(size_t)c * N + i];
  float v = s / l;
  out[tid] = v > 0.f ? v : expm1f(v);
}

// ---------------------------------------------------------------------------
extern "C" void kernel_launch(void* const* d_in, const int* in_sizes, int n_in,
                              void* d_out, int out_size, void* d_ws,
                              size_t ws_size, hipStream_t stream) {
  const float* x = (const float*)d_in[0];
  const int* adj = (const int*)d_in[1];
  const float* W = (const float*)d_in[2];
  const float* a = (const float*)d_in[3];
  float* out = (float*)d_out;

  char* ws = (char*)d_ws;
  _Float16* Wh_t = (_Float16*)ws;                      // 1 MiB
  float* s1 = (float*)(ws + (size_t)N * OUT_DIM * 2);  // 32 KiB
  float* s2 = s1 + N;                                  // 32 KiB
  float* M = s2 + N;                                   // 4 B
  float* accp = (float*)(ws + (2u << 20));             // JC*N*64*4 = 16 MiB
  float* lp = accp + (size_t)JC * N * OUT_DIM;         // JC*N*4 = 256 KiB

  wh_kernel<<<N, 64, 0, stream>>>(x, W, a, Wh_t, s1, s2);
  max_kernel<<<1, 256, 0, stream>>>(s1, s2, M);
  attn_kernel<<<dim3(N / 64, JC), 256, 0, stream>>>(adj, Wh_t, s1, s2, M,
                                                    accp, lp);
  reduce_kernel<<<N * OUT_DIM / 256, 256, 0, stream>>>(accp, lp, out);
}